// Round 7
// baseline (21099.393 us; speedup 1.0000x reference)
//
#include <hip/hip_runtime.h>
#include <math.h>

#define BB 32
#define EE 256
#define HH 512
#define VV 32000
#define TT 64
#define GO_ID 2
#define EOS_ID 3

// ======================= fused persistent path =======================
#define NB3 250
#define NT3 512
#define RPB 128            // W rows per block per step
#define NCH 16             // k-chunks (32 floats = 8 float4 each)
#define WROW 9             // float4 stride per row in LDS tile (8 + 1 pad)

// ws layout (float offsets)
#define WS2_H0   0            // h ping: [c4][b] interleaved, 16384 floats
#define WS2_H1   16384        // h pong
#define WS2_P4   32768        // part4: 250*32 float4
#define WS2_SYNC 65536        // sync ints: pcnt[64]*32, gcnt[64]*32, hrdy[64]*32
#define WS2_SYNC_BYTES (3*64*32*4)

// out layout (floats)
#define OUT_WO   65536000ULL
#define OUT_EMB  (OUT_WO + 2048ULL)
#define OUT_LEN  (OUT_EMB + 524288ULL)

__device__ __forceinline__ void merge_sm(float& m, float& s, float& av, int& ai,
                                         float m2, float s2, float av2, int ai2)
{
    float mn = fmaxf(m, m2);
    s = s*expf(m - mn) + s2*expf(m2 - mn);
    m = mn;
    if (av2 > av || (av2 == av && ai2 < ai)) { av = av2; ai = ai2; }
}

// ---- producer/consumer sync primitives (flags pre-zeroed by hipMemsetAsync) ----
// add-and-maybe-signal: last arriver sets flag (release chains make all prior
// stores of all arrivers visible to any acquirer of the flag)
__device__ __forceinline__ void sig_add_last(int* cnt, int* flag, int nlast, int tid)
{
    __syncthreads();   // all block stores done before the release add
    if (tid == 0) {
        int old = __hip_atomic_fetch_add(cnt, 1, __ATOMIC_ACQ_REL, __HIP_MEMORY_SCOPE_AGENT);
        if (old == nlast - 1)
            __hip_atomic_store(flag, 1, __ATOMIC_RELEASE, __HIP_MEMORY_SCOPE_AGENT);
    }
}
// fire-and-forget count (workers never wait on this)
__device__ __forceinline__ void cnt_add(int* cnt, int tid)
{
    __syncthreads();
    if (tid == 0)
        __hip_atomic_fetch_add(cnt, 1, __ATOMIC_ACQ_REL, __HIP_MEMORY_SCOPE_AGENT);
}
__device__ __forceinline__ void wait_flag(const int* flag, int tid)
{
    if (tid == 0) {
        while (__hip_atomic_load(flag, __ATOMIC_ACQUIRE, __HIP_MEMORY_SCOPE_AGENT) == 0)
            __builtin_amdgcn_s_sleep(4);
    }
    __syncthreads();
}
__device__ __forceinline__ void wait_cnt(const int* cnt, int target, int tid)
{
    if (tid == 0) {
        while (__hip_atomic_load(cnt, __ATOMIC_ACQUIRE, __HIP_MEMORY_SCOPE_AGENT) < target)
            __builtin_amdgcn_s_sleep(8);
    }
    __syncthreads();
}

struct SmemT {
    float4 wbuf[2][RPB*WROW];   // 36864 B : W tile double buffer
    float4 redSm[1024];         // 16384 B : partials; aliased as gruS (12 KB) in GRU
    float  mprev[32];
    float  sprev[32];
    int    toksS[32];
};

// GRU cell phase for 512-thread blocks; block bk handles k rows bk*4..bk*4+3 (proven r2-r6)
__device__ __forceinline__ void gru_phase(
    int bk, int tid, bool init, const int* toks,
    const float* __restrict__ emb,
    const float* __restrict__ Wih, const float* __restrict__ bih,
    const float* __restrict__ Whh, const float* __restrict__ bhh,
    const float* __restrict__ h0, const float* __restrict__ hprevT,
    float* __restrict__ hTout, float* __restrict__ gruS)
{
    const int b   = tid & 31;
    const int q   = tid >> 5;     // 0..15
    const int ko  = q & 3;
    const int seg = q >> 2;       // 0..3
    const int k   = bk*4 + ko;
    const int tok = init ? GO_ID : toks[b];

    float s_ir = 0.f, s_iz = 0.f, s_in = 0.f;
    {
        const float4* x4 = (const float4*)emb + (size_t)tok*64;
        const float4* wr = (const float4*)Wih + (size_t)k*64;
        const float4* wz = (const float4*)Wih + (size_t)(HH + k)*64;
        const float4* wn = (const float4*)Wih + (size_t)(2*HH + k)*64;
#pragma unroll
        for (int i = 0; i < 16; ++i) {
            int c = seg*16 + i;
            float4 xv = x4[c];
            float4 a  = wr[c]; s_ir += a.x*xv.x + a.y*xv.y + a.z*xv.z + a.w*xv.w;
            float4 bz = wz[c]; s_iz += bz.x*xv.x + bz.y*xv.y + bz.z*xv.z + bz.w*xv.w;
            float4 cn = wn[c]; s_in += cn.x*xv.x + cn.y*xv.y + cn.z*xv.z + cn.w*xv.w;
        }
    }
    float s_hr = 0.f, s_hz = 0.f, s_hn = 0.f;
    {
        const float4* wr = (const float4*)Whh + (size_t)k*128;
        const float4* wz = (const float4*)Whh + (size_t)(HH + k)*128;
        const float4* wn = (const float4*)Whh + (size_t)(2*HH + k)*128;
        const float4* h4 = init ? ((const float4*)h0 + b*128) : ((const float4*)hprevT);
#pragma unroll
        for (int i = 0; i < 32; ++i) {
            int c = seg*32 + i;
            float4 hv = init ? h4[c] : h4[c*32 + b];
            float4 a  = wr[c]; s_hr += a.x*hv.x + a.y*hv.y + a.z*hv.z + a.w*hv.w;
            float4 bz = wz[c]; s_hz += bz.x*hv.x + bz.y*hv.y + bz.z*hv.z + bz.w*hv.w;
            float4 cn = wn[c]; s_hn += cn.x*hv.x + cn.y*hv.y + cn.z*hv.z + cn.w*hv.w;
        }
    }
    const int si = (q*32 + b)*6;
    gruS[si+0] = s_ir; gruS[si+1] = s_iz; gruS[si+2] = s_in;
    gruS[si+3] = s_hr; gruS[si+4] = s_hz; gruS[si+5] = s_hn;
    __syncthreads();
    if (q < 4) {
        const int kk = bk*4 + q;
        float ir = bih[kk], iz = bih[HH + kk], inn = bih[2*HH + kk];
        float hr = bhh[kk], hz = bhh[HH + kk], hn  = bhh[2*HH + kk];
#pragma unroll
        for (int s2 = 0; s2 < 4; ++s2) {
            int base = ((s2*4 + q)*32 + b)*6;
            ir += gruS[base+0]; iz += gruS[base+1]; inn += gruS[base+2];
            hr += gruS[base+3]; hz += gruS[base+4]; hn  += gruS[base+5];
        }
        float r = 1.f/(1.f + expf(-(ir + hr)));
        float z = 1.f/(1.f + expf(-(iz + hz)));
        float n = tanhf(inn + r*hn);
        float hp = init ? h0[b*HH + kk] : hprevT[(kk>>2)*128 + b*4 + (kk&3)];
        hTout[(kk>>2)*128 + b*4 + (kk&3)] = (1.f - z)*n + z*hp;
    }
}

__global__ __launch_bounds__(NT3)
void fused4(const float* __restrict__ emb,
            const float* __restrict__ Wih, const float* __restrict__ bih,
            const float* __restrict__ Whh, const float* __restrict__ bhh,
            const float* __restrict__ Wout, const float* __restrict__ bout,
            const float* __restrict__ h0,
            float* __restrict__ out, float* __restrict__ ws)
{
    const int blk = blockIdx.x, tid = threadIdx.x;

    float* hb0 = ws + WS2_H0;
    float* hb1 = ws + WS2_H1;
    float4* part4 = (float4*)(ws + WS2_P4);
    int* pcnt = (int*)(ws + WS2_SYNC);      // [64] stride 32 ints
    int* gcnt = pcnt + 64*32;               // [64] stride 32 ints
    int* hrdy = pcnt + 2*64*32;             // [64] stride 32 ints

    float* w_pro  = out;
    float* w_o    = out + OUT_WO;
    float* emb_sq = out + OUT_EMB;
    float* len_o  = out + OUT_LEN;

    __shared__ SmemT sm;
    float* gruS = (float*)sm.redSm;          // alias (phases don't overlap)

    const bool is_gru = (blk >= 64 && blk < 192);
    int flag_reg = 0;                        // per-batch EOS flag (blocks 0..31)
    int len_b = 0;

    // ---- h(0) = GRU(emb[GO], h0) -> hb0; last GRU block raises hrdy[0]
    if (is_gru) {
        gru_phase(blk-64, tid, true, sm.toksS, emb, Wih, bih, Whh, bhh, h0, nullptr, hb0, gruS);
        sig_add_last(&gcnt[0], &hrdy[0], 128, tid);
    }

    const int bgrp  = tid & 15;        // 16 batch-pairs
    const int rslot = tid >> 4;        // 0..31 row groups (4 rows each)
    const int b0    = bgrp*2;
    const int v0    = blk*RPB;
    const float4* W4 = (const float4*)Wout;

    for (int t = 0; t < TT; ++t) {
        const float* hT  = (t & 1) ? hb1 : hb0;
        float*       hNx = (t & 1) ? hb0 : hb1;
        const float4* hT4 = (const float4*)hT;

        // ---- pre-stage W chunk 0 (h-independent) while h may still be in flight
        {
#pragma unroll
            for (int i = 0; i < 2; ++i) {
                int off = i*512 + tid;            // 0..1023
                int r = off >> 3, k4 = off & 7;
                sm.wbuf[0][r*WROW + k4] = W4[(size_t)(v0 + r)*128 + k4];
            }
        }
        // ---- wait for h(t) (also fences the wbuf[0] writes block-wide)
        wait_flag(&hrdy[t*32], tid);

        // ================= Phase L: logits (128 rows x 32 batch) into registers =================
        float acc0[4] = {0.f,0.f,0.f,0.f};
        float acc1[4] = {0.f,0.f,0.f,0.f};

        for (int c = 0; c < NCH; ++c) {
            float4 st[2];
            if (c < NCH-1) {
#pragma unroll
                for (int i = 0; i < 2; ++i) {
                    int off = i*512 + tid;
                    int r = off >> 3, k4 = off & 7;
                    st[i] = W4[(size_t)(v0 + r)*128 + (c+1)*8 + k4];
                }
            }
            const float4* wb = sm.wbuf[c & 1];
#pragma unroll
            for (int c4 = 0; c4 < 8; ++c4) {
                const int c4g = c*8 + c4;
                float4 h0v = hT4[c4g*32 + b0];
                float4 h1v = hT4[c4g*32 + b0 + 1];
#pragma unroll
                for (int i = 0; i < 4; ++i) {
                    float4 w = wb[(rslot*4 + i)*WROW + c4];
                    acc0[i] += w.x*h0v.x + w.y*h0v.y + w.z*h0v.z + w.w*h0v.w;
                    acc1[i] += w.x*h1v.x + w.y*h1v.y + w.z*h1v.z + w.w*h1v.w;
                }
            }
            if (c < NCH-1) {
#pragma unroll
                for (int i = 0; i < 2; ++i) {
                    int off = i*512 + tid;
                    int r = off >> 3, k4 = off & 7;
                    sm.wbuf[(c+1) & 1][r*WROW + k4] = st[i];
                }
            }
            __syncthreads();
        }

        // epilogue: bias, per-thread softmax/argmax partials (logits stay in regs)
        {
            const int vb = v0 + rslot*4;
#pragma unroll
            for (int i = 0; i < 4; ++i) {
                float bb_ = bout[vb + i];
                acc0[i] += bb_; acc1[i] += bb_;
            }
            float m0 = -INFINITY, s0 = 0.f, av0 = -INFINITY; int ai0 = 0x7fffffff;
            float m1 = -INFINITY, s1 = 0.f, av1 = -INFINITY; int ai1 = 0x7fffffff;
#pragma unroll
            for (int i = 0; i < 4; ++i) {
                int v = vb + i;
                float val = acc0[i];
                if (val > m0) { s0 = s0*expf(m0 - val) + 1.f; m0 = val; }
                else          { s0 += expf(val - m0); }
                if (v >= 2 && val > av0) { av0 = val; ai0 = v; }
                float vl1 = acc1[i];
                if (vl1 > m1) { s1 = s1*expf(m1 - vl1) + 1.f; m1 = vl1; }
                else          { s1 += expf(vl1 - m1); }
                if (v >= 2 && vl1 > av1) { av1 = vl1; ai1 = v; }
            }
            sm.redSm[b0*32 + rslot]     = make_float4(m0, s0, av0, __int_as_float(ai0));
            sm.redSm[(b0+1)*32 + rslot] = make_float4(m1, s1, av1, __int_as_float(ai1));
        }
        __syncthreads();
        if (tid < 32) {
            float4 p0 = sm.redSm[tid*32];
            float m = p0.x, s = p0.y, av = p0.z; int ai = __float_as_int(p0.w);
            for (int j = 1; j < 32; ++j) {
                float4 p = sm.redSm[tid*32 + j];
                merge_sm(m, s, av, ai, p.x, p.y, p.z, __float_as_int(p.w));
            }
            part4[(size_t)blk*32 + tid] = make_float4(m, s, av, __int_as_float(ai));
        }
        // publish partials (fire-and-forget), then wait for all 250
        cnt_add(&pcnt[t*32], tid);
        wait_cnt(&pcnt[t*32], NB3, tid);

        // ================= redundant reduce: every block derives toks/m/s locally =================
        {
            int b = tid & 31, jg = tid >> 5;   // jg 0..15
            float m = -INFINITY, s = 0.f, av = -INFINITY; int ai = 0x7fffffff;
#pragma unroll
            for (int i = 0; i < 16; ++i) {
                int j = jg + 16*i;
                if (j < NB3) {
                    float4 p = part4[(size_t)j*32 + b];
                    merge_sm(m, s, av, ai, p.x, p.y, p.z, __float_as_int(p.w));
                }
            }
            sm.redSm[tid] = make_float4(m, s, av, __int_as_float(ai));
        }
        __syncthreads();
        if (tid < 32) {
            float4 p0 = sm.redSm[tid];
            float m = p0.x, s = p0.y, av = p0.z; int ai = __float_as_int(p0.w);
#pragma unroll
            for (int i = 1; i < 16; ++i) {
                float4 p = sm.redSm[tid + 32*i];
                merge_sm(m, s, av, ai, p.x, p.y, p.z, __float_as_int(p.w));
            }
            sm.mprev[tid] = m; sm.sprev[tid] = 1.f/s; sm.toksS[tid] = ai;
        }
        __syncthreads();

        // ---- GRU first (gets h(t+1) out on the critical path ASAP)
        if (is_gru && t < TT-1) {
            gru_phase(blk-64, tid, false, sm.toksS, emb, Wih, bih, Whh, bhh, h0, hT, hNx, gruS);
            sig_add_last(&gcnt[(t+1)*32], &hrdy[(t+1)*32], 128, tid);
        }

        // ---- outputs (blocks 0..31 own batch == blk)
        if (blk < BB) {
            const int tok   = sm.toksS[blk];
            const int alive = flag_reg ? 0 : 1;
            if (tid == 0) w_o[(size_t)t*BB + blk] = alive ? (float)tok : 0.f;
            len_b += alive;
            if (tid < EE) {
                float e = alive ? emb[(size_t)tok*EE + tid] : 0.f;
                emb_sq[(size_t)t*8192 + blk*EE + tid] = e;
            }
            flag_reg |= (tok == EOS_ID) ? 1 : 0;
            if (t == TT-1 && tid == 32) len_o[blk] = (float)len_b;
        }

        // ---- normalized w_pro write straight from registers
        {
            const int vb = v0 + rslot*4;
            float* wpt = w_pro + (size_t)t*1024000;
            float m0 = sm.mprev[b0],   si0 = sm.sprev[b0];
            float m1 = sm.mprev[b0+1], si1 = sm.sprev[b0+1];
            float4 o0 = make_float4(expf(acc0[0]-m0)*si0, expf(acc0[1]-m0)*si0,
                                    expf(acc0[2]-m0)*si0, expf(acc0[3]-m0)*si0);
            float4 o1 = make_float4(expf(acc1[0]-m1)*si1, expf(acc1[1]-m1)*si1,
                                    expf(acc1[2]-m1)*si1, expf(acc1[3]-m1)*si1);
            *(float4*)(wpt + (size_t)b0*VV + vb)     = o0;
            *(float4*)(wpt + (size_t)(b0+1)*VV + vb) = o1;
        }
        __syncthreads();   // sm reuse safety before next iteration
    }
}

// ======================= fallback multi-launch path (round-2, proven) =======================
#define NBL 500
#define NT  256
#define WS_HT0   0
#define WS_HT1   16384
#define WS_X     32768
#define WS_PART  40960
#define WS_M     104960
#define WS_SINV  104992
#define WS_INT   105024

__global__ __launch_bounds__(NT)
void k_init(const float* __restrict__ emb, float* __restrict__ ws)
{
    float* xbuf = ws + WS_X;
    int* toki  = (int*)(ws + WS_INT);
    int* flags = toki;
    int* lenac = toki + 32;
    xbuf[blockIdx.x*EE + threadIdx.x] = emb[GO_ID*EE + threadIdx.x];
    if (blockIdx.x == 0 && threadIdx.x < BB) { flags[threadIdx.x] = 0; lenac[threadIdx.x] = 0; }
}

__global__ __launch_bounds__(NT)
void k_gru(const float* __restrict__ Wih, const float* __restrict__ bih,
           const float* __restrict__ Whh, const float* __restrict__ bhh,
           const float* __restrict__ h0, float* __restrict__ ws, int t)
{
    const int blk = blockIdx.x, tid = threadIdx.x;
    float* hTprev = ws + (((t & 1) == 0) ? WS_HT1 : WS_HT0);
    float* hTcur  = ws + (((t & 1) == 0) ? WS_HT0 : WS_HT1);
    const float* xbuf = ws + WS_X;

    __shared__ float smem[1536];

    const int b    = tid & 31;
    const int q    = tid >> 5;
    const int k    = blk*4 + (q & 3);
    const int half = q >> 2;

    float s_ir = 0.f, s_iz = 0.f, s_in = 0.f;
    {
        const float4* x4 = (const float4*)xbuf + b*64;
        const float4* wr = (const float4*)Wih + (size_t)k*64;
        const float4* wz = (const float4*)Wih + (size_t)(HH + k)*64;
        const float4* wn = (const float4*)Wih + (size_t)(2*HH + k)*64;
        const int c0 = half*32, c1 = c0 + 32;
        for (int c4 = c0; c4 < c1; ++c4) {
            float4 xv = x4[c4];
            float4 a  = wr[c4]; s_ir += a.x*xv.x + a.y*xv.y + a.z*xv.z + a.w*xv.w;
            float4 bz = wz[c4]; s_iz += bz.x*xv.x + bz.y*xv.y + bz.z*xv.z + bz.w*xv.w;
            float4 cn = wn[c4]; s_in += cn.x*xv.x + cn.y*xv.y + cn.z*xv.z + cn.w*xv.w;
        }
    }
    float s_hr = 0.f, s_hz = 0.f, s_hn = 0.f;
    {
        const float4* wr = (const float4*)Whh + (size_t)k*128;
        const float4* wz = (const float4*)Whh + (size_t)(HH + k)*128;
        const float4* wn = (const float4*)Whh + (size_t)(2*HH + k)*128;
        const int c0 = half*64, c1 = c0 + 64;
        if (t == 0) {
            const float4* h4 = (const float4*)h0 + b*128;
            for (int c4 = c0; c4 < c1; ++c4) {
                float4 hv = h4[c4];
                float4 a  = wr[c4]; s_hr += a.x*hv.x + a.y*hv.y + a.z*hv.z + a.w*hv.w;
                float4 bz = wz[c4]; s_hz += bz.x*hv.x + bz.y*hv.y + bz.z*hv.z + bz.w*hv.w;
                float4 cn = wn[c4]; s_hn += cn.x*hv.x + cn.y*hv.y + cn.z*hv.z + cn.w*hv.w;
            }
        } else {
            const float4* h4 = (const float4*)hTprev;
            for (int c4 = c0; c4 < c1; ++c4) {
                float4 hv = h4[c4*32 + b];
                float4 a  = wr[c4]; s_hr += a.x*hv.x + a.y*hv.y + a.z*hv.z + a.w*hv.w;
                float4 bz = wz[c4]; s_hz += bz.x*hv.x + bz.y*hv.y + bz.z*hv.z + bz.w*hv.w;
                float4 cn = wn[c4]; s_hn += cn.x*hv.x + cn.y*hv.y + cn.z*hv.z + cn.w*hv.w;
            }
        }
    }
    const int si = (q*32 + b)*6;
    smem[si+0] = s_ir; smem[si+1] = s_iz; smem[si+2] = s_in;
    smem[si+3] = s_hr; smem[si+4] = s_hz; smem[si+5] = s_hn;
    __syncthreads();
    if (q < 4) {
        const int i0 = (q*32 + b)*6, i1 = ((q+4)*32 + b)*6;
        float ir  = smem[i0+0] + smem[i1+0] + bih[k];
        float iz  = smem[i0+1] + smem[i1+1] + bih[HH + k];
        float inn = smem[i0+2] + smem[i1+2] + bih[2*HH + k];
        float hr  = smem[i0+3] + smem[i1+3] + bhh[k];
        float hz  = smem[i0+4] + smem[i1+4] + bhh[HH + k];
        float hn  = smem[i0+5] + smem[i1+5] + bhh[2*HH + k];
        float r = 1.f/(1.f + expf(-(ir + hr)));
        float z = 1.f/(1.f + expf(-(iz + hz)));
        float n = tanhf(inn + r*hn);
        float hp = (t == 0) ? h0[b*HH + k] : hTprev[(k>>2)*128 + b*4 + (k&3)];
        float hv = (1.f - z)*n + z*hp;
        hTcur[(k>>2)*128 + b*4 + (k&3)] = hv;
    }
}

__global__ __launch_bounds__(NT)
void k_logits(const float* __restrict__ Wout, const float* __restrict__ bout,
              float* __restrict__ out, float* __restrict__ ws, int t)
{
    const int blk = blockIdx.x, tid = threadIdx.x;
    const float* hTcur = ws + (((t & 1) == 0) ? WS_HT0 : WS_HT1);
    float* part  = ws + WS_PART;
    const float* Mrow  = ws + WS_M;
    const float* SinvA = ws + WS_SINV;
    float* w_pro = out;

    __shared__ float smem[2080];

    if (t > 0) {
        float* wp = w_pro + (size_t)(t-1)*1024000 + blk*64;
        const int vl = tid & 63, bq = tid >> 6;
#pragma unroll
        for (int r = 0; r < 8; ++r) {
            int b = r*4 + bq;
            size_t idx = (size_t)b*VV + vl;
            wp[idx] = expf(wp[idx] - Mrow[b]) * SinvA[b];
        }
    }

    const int b  = tid & 31;
    const int vg = tid >> 5;
    const int v0 = blk*64 + vg*8;
    float acc[8] = {0.f,0.f,0.f,0.f,0.f,0.f,0.f,0.f};
    const float4* hT4  = (const float4*)hTcur;
    const float4* wrow = (const float4*)Wout + (size_t)v0*128;
    for (int c4 = 0; c4 < 128; ++c4) {
        float4 hv = hT4[c4*32 + b];
#pragma unroll
        for (int i = 0; i < 8; ++i) {
            float4 wv = wrow[(size_t)i*128 + c4];
            acc[i] += wv.x*hv.x + wv.y*hv.y + wv.z*hv.z + wv.w*hv.w;
        }
    }
    __syncthreads();
#pragma unroll
    for (int i = 0; i < 8; ++i)
        smem[b*65 + vg*8 + i] = acc[i] + bout[v0 + i];
    __syncthreads();
    {
        float* wp = w_pro + (size_t)t*1024000 + blk*64;
        const int vl = tid & 63, bq = tid >> 6;
#pragma unroll
        for (int r = 0; r < 8; ++r) {
            int b2 = r*4 + bq;
            wp[(size_t)b2*VV + vl] = smem[b2*65 + vl];
        }
    }
    {
        const int rb = tid >> 3, l = tid & 7;
        float m = -INFINITY, s = 0.f, av = -INFINITY; int ai = 0;
        for (int j = l; j < 64; j += 8) {
            float val = smem[rb*65 + j];
            if (val > m) { s = s*expf(m - val) + 1.f; m = val; }
            else         { s += expf(val - m); }
            int vglob = blk*64 + j;
            if (vglob >= 2 && val > av) { av = val; ai = vglob; }
        }
        for (int d = 1; d < 8; d <<= 1) {
            float m2  = __shfl_xor(m, d);
            float s2  = __shfl_xor(s, d);
            float av2 = __shfl_xor(av, d);
            int   ai2 = __shfl_xor(ai, d);
            float mn = fmaxf(m, m2);
            s = s*expf(m - mn) + s2*expf(m2 - mn); m = mn;
            if (av2 > av || (av2 == av && ai2 < ai)) { av = av2; ai = ai2; }
        }
        if (l == 0)
            ((float4*)part)[blk*32 + rb] = make_float4(m, s, av, __int_as_float(ai));
    }
}

__global__ __launch_bounds__(NT)
void k_reduce(const float* __restrict__ emb, float* __restrict__ out,
              float* __restrict__ ws, int t)
{
    const int b = blockIdx.x, tid = threadIdx.x;
    const float* part = ws + WS_PART;
    float* Mrow  = ws + WS_M;
    float* SinvA = ws + WS_SINV;
    int*   flags = (int*)(ws + WS_INT);
    int*   lenac = flags + 32;
    float* xbuf  = ws + WS_X;

    float* w_o    = out + OUT_WO;
    float* emb_sq = out + OUT_EMB;
    float* len_o  = out + OUT_LEN;

    __shared__ float smem[32];

    float m = -INFINITY, s = 0.f, av = -INFINITY; int ai = 0;
    for (int j = tid; j < NBL; j += NT) {
        float4 p = ((const float4*)part)[j*32 + b];
        float mn = fmaxf(m, p.x);
        s = s*expf(m - mn) + p.y*expf(p.x - mn); m = mn;
        int aij = __float_as_int(p.w);
        if (p.z > av || (p.z == av && aij < ai)) { av = p.z; ai = aij; }
    }
    for (int d = 1; d < 64; d <<= 1) {
        float m2  = __shfl_xor(m, d);
        float s2  = __shfl_xor(s, d);
        float av2 = __shfl_xor(av, d);
        int   ai2 = __shfl_xor(ai, d);
        float mn = fmaxf(m, m2);
        s = s*expf(m - mn) + s2*expf(m2 - mn); m = mn;
        if (av2 > av || (av2 == av && ai2 < ai)) { av = av2; ai = ai2; }
    }
    const int wid = tid >> 6, lane = tid & 63;
    if (lane == 0) {
        smem[wid*4+0] = m; smem[wid*4+1] = s;
        smem[wid*4+2] = av; smem[wid*4+3] = __int_as_float(ai);
    }
    __syncthreads();
    if (tid == 0) {
        float M = smem[0], S = smem[1], AV = smem[2];
        int AI = __float_as_int(smem[3]);
        for (int w2 = 1; w2 < 4; ++w2) {
            float m2 = smem[w2*4], s2 = smem[w2*4+1], av2 = smem[w2*4+2];
            int ai2 = __float_as_int(smem[w2*4+3]);
            float mn = fmaxf(M, m2);
            S = S*expf(M - mn) + s2*expf(m2 - mn); M = mn;
            if (av2 > AV || (av2 == AV && ai2 < AI)) { AV = av2; AI = ai2; }
        }
        Mrow[b] = M; SinvA[b] = 1.f/S;
        int fl = flags[b];
        int alive = fl ? 0 : 1;
        w_o[t*BB + b] = alive ? (float)AI : 0.f;
        flags[b] = fl | (AI == EOS_ID ? 1 : 0);
        lenac[b] += alive;
        if (t == TT-1) len_o[b] = (float)lenac[b];
        smem[16] = __int_as_float(AI);
        smem[17] = (float)alive;
    }
    __syncthreads();
    const int tok = __float_as_int(smem[16]);
    const float alive = smem[17];
    float e = emb[(size_t)tok*EE + tid];
    xbuf[b*EE + tid] = e;
    emb_sq[(size_t)t*8192 + b*EE + tid] = alive * e;
}

__global__ __launch_bounds__(NT)
void k_norm_last(float* __restrict__ out, float* __restrict__ ws)
{
    const int blk = blockIdx.x, tid = threadIdx.x;
    const float* Mrow  = ws + WS_M;
    const float* SinvA = ws + WS_SINV;
    float* wp = out + (size_t)(TT-1)*1024000 + blk*64;
    const int vl = tid & 63, bq = tid >> 6;
#pragma unroll
    for (int r = 0; r < 8; ++r) {
        int b = r*4 + bq;
        size_t idx = (size_t)b*VV + vl;
        wp[idx] = expf(wp[idx] - Mrow[b]) * SinvA[b];
    }
}

extern "C" void kernel_launch(void* const* d_in, const int* in_sizes, int n_in,
                              void* d_out, int out_size, void* d_ws, size_t ws_size,
                              hipStream_t stream)
{
    const float* emb  = (const float*)d_in[0];
    const float* Wih  = (const float*)d_in[1];
    const float* bih  = (const float*)d_in[2];
    const float* Whh  = (const float*)d_in[3];
    const float* bhh  = (const float*)d_in[4];
    const float* Wout = (const float*)d_in[5];
    const float* bout = (const float*)d_in[6];
    const float* h0   = (const float*)d_in[7];
    float* out = (float*)d_out;
    float* ws  = (float*)d_ws;

    // zero the per-step counters/flags (stream-ordered; part of the captured graph)
    hipError_t err = hipMemsetAsync((char*)d_ws + (size_t)WS2_SYNC*4, 0, WS2_SYNC_BYTES, stream);

    if (err == hipSuccess) {
        void* args[] = { (void*)&emb, (void*)&Wih, (void*)&bih, (void*)&Whh, (void*)&bhh,
                         (void*)&Wout, (void*)&bout, (void*)&h0, (void*)&out, (void*)&ws };
        err = hipLaunchCooperativeKernel((const void*)fused4,
                                         dim3(NB3), dim3(NT3), args, 0, stream);
    }
    if (err != hipSuccess) {
        (void)hipGetLastError();   // clear sticky error; use proven multi-launch path
        hipLaunchKernelGGL(k_init, dim3(BB), dim3(NT), 0, stream, emb, ws);
        for (int t = 0; t < TT; ++t) {
            hipLaunchKernelGGL(k_gru,    dim3(128), dim3(NT), 0, stream, Wih, bih, Whh, bhh, h0, ws, t);
            hipLaunchKernelGGL(k_logits, dim3(NBL), dim3(NT), 0, stream, Wout, bout, out, ws, t);
            hipLaunchKernelGGL(k_reduce, dim3(BB),  dim3(NT), 0, stream, emb, out, ws, t);
        }
        hipLaunchKernelGGL(k_norm_last, dim3(NBL), dim3(NT), 0, stream, out, ws);
    }
}

// Round 9
// 10060.807 us; speedup vs baseline: 2.0972x; 2.0972x over previous
//
#include <hip/hip_runtime.h>
#include <math.h>

#define BB 32
#define EE 256
#define HH 512
#define VV 32000
#define TT 64
#define GO_ID 2
#define EOS_ID 3

// ======================= fused persistent path =======================
#define NB3 250
#define NT3 512
#define RPB 128            // W rows per block per step
#define NCH 16             // k-chunks (32 floats = 8 float4 each)
#define WROW 9             // float4 stride per row in LDS tile (8 + 1 pad)
#define NEG_SENT (-3.0e38f)

// ---- ws arenas (float offsets), all step-indexed => consumer caches never hold stale copies
#define H_OFF   0u                    // h[t]: [64][16384]  (4 MB)
#define H_STEP  16384u
#define P_OFF   1048576u              // part[t][blk][b][4]: [64][250][32][4] (8 MB)
#define P_STEP  32000u
#define F_OFF   3096576u              // final[t][b][4]: m, 1/s, unused, tok  (32 KB)
#define F_STEP  128u
#define FLAG_OFF 3104768u             // ints from here
#define PF_OFF  0u                    // pflag[t*250+blk]
#define FF_OFF  16000u                // fflag[t*32+b]
#define HF_OFF  18048u                // hflag[t*128+i]
#define FLAG_INTS 26240u
#define WS_NEEDED_BYTES ((3104768ull + 26240ull) * 4ull)

// out layout (floats)
#define OUT_WO   65536000ULL
#define OUT_EMB  (OUT_WO + 2048ULL)
#define OUT_LEN  (OUT_EMB + 524288ULL)

__device__ __forceinline__ void merge_sm(float& m, float& s, float& av, int& ai,
                                         float m2, float s2, float av2, int ai2)
{
    float mn = fmaxf(m, m2);
    s = s*expf(m - mn) + s2*expf(m2 - mn);
    m = mn;
    if (av2 > av || (av2 == av && ai2 < ai)) { av = av2; ai = ai2; }
}

// relaxed agent-scope primitives (sc1: straight to coherence point, no L2 wb/inv storms)
__device__ __forceinline__ void stf(float* p, float v)
{ __hip_atomic_store(p, v, __ATOMIC_RELAXED, __HIP_MEMORY_SCOPE_AGENT); }
__device__ __forceinline__ void sti(int* p, int v)
{ __hip_atomic_store(p, v, __ATOMIC_RELAXED, __HIP_MEMORY_SCOPE_AGENT); }
__device__ __forceinline__ int ldi(const int* p)
{ return __hip_atomic_load(p, __ATOMIC_RELAXED, __HIP_MEMORY_SCOPE_AGENT); }
__device__ __forceinline__ float ldf(const float* p)
{ return __hip_atomic_load(p, __ATOMIC_RELAXED, __HIP_MEMORY_SCOPE_AGENT); }

struct SmemT {
    float4 wbuf[2][RPB*WROW];   // 36864 B : W tile double buffer
    float4 redSm[1024];         // 16384 B : partials; aliased as gruS in GRU phase
    float  mprev[32];
    float  sprev[32];
    int    toksS[32];
};

// GRU cell phase; block bk handles k rows bk*4..bk*4+3; h output via relaxed atomics
__device__ __forceinline__ void gru_phase(
    int bk, int tid, bool init, const int* toks,
    const float* __restrict__ emb,
    const float* __restrict__ Wih, const float* __restrict__ bih,
    const float* __restrict__ Whh, const float* __restrict__ bhh,
    const float* __restrict__ h0, const float* __restrict__ hprevT,
    float* __restrict__ hTout, float* __restrict__ gruS)
{
    const int b   = tid & 31;
    const int q   = tid >> 5;     // 0..15
    const int ko  = q & 3;
    const int seg = q >> 2;       // 0..3
    const int k   = bk*4 + ko;
    const int tok = init ? GO_ID : toks[b];

    float s_ir = 0.f, s_iz = 0.f, s_in = 0.f;
    {
        const float4* x4 = (const float4*)emb + (size_t)tok*64;
        const float4* wr = (const float4*)Wih + (size_t)k*64;
        const float4* wz = (const float4*)Wih + (size_t)(HH + k)*64;
        const float4* wn = (const float4*)Wih + (size_t)(2*HH + k)*64;
#pragma unroll
        for (int i = 0; i < 16; ++i) {
            int c = seg*16 + i;
            float4 xv = x4[c];
            float4 a  = wr[c]; s_ir += a.x*xv.x + a.y*xv.y + a.z*xv.z + a.w*xv.w;
            float4 bz = wz[c]; s_iz += bz.x*xv.x + bz.y*xv.y + bz.z*xv.z + bz.w*xv.w;
            float4 cn = wn[c]; s_in += cn.x*xv.x + cn.y*xv.y + cn.z*xv.z + cn.w*xv.w;
        }
    }
    float s_hr = 0.f, s_hz = 0.f, s_hn = 0.f;
    {
        const float4* wr = (const float4*)Whh + (size_t)k*128;
        const float4* wz = (const float4*)Whh + (size_t)(HH + k)*128;
        const float4* wn = (const float4*)Whh + (size_t)(2*HH + k)*128;
        const float4* h4 = init ? ((const float4*)h0 + b*128) : ((const float4*)hprevT);
#pragma unroll
        for (int i = 0; i < 32; ++i) {
            int c = seg*32 + i;
            float4 hv = init ? h4[c] : h4[c*32 + b];
            float4 a  = wr[c]; s_hr += a.x*hv.x + a.y*hv.y + a.z*hv.z + a.w*hv.w;
            float4 bz = wz[c]; s_hz += bz.x*hv.x + bz.y*hv.y + bz.z*hv.z + bz.w*hv.w;
            float4 cn = wn[c]; s_hn += cn.x*hv.x + cn.y*hv.y + cn.z*hv.z + cn.w*hv.w;
        }
    }
    const int si = (q*32 + b)*6;
    gruS[si+0] = s_ir; gruS[si+1] = s_iz; gruS[si+2] = s_in;
    gruS[si+3] = s_hr; gruS[si+4] = s_hz; gruS[si+5] = s_hn;
    __syncthreads();
    if (q < 4) {
        const int kk = bk*4 + q;
        float ir = bih[kk], iz = bih[HH + kk], inn = bih[2*HH + kk];
        float hr = bhh[kk], hz = bhh[HH + kk], hn  = bhh[2*HH + kk];
#pragma unroll
        for (int s2 = 0; s2 < 4; ++s2) {
            int base = ((s2*4 + q)*32 + b)*6;
            ir += gruS[base+0]; iz += gruS[base+1]; inn += gruS[base+2];
            hr += gruS[base+3]; hz += gruS[base+4]; hn  += gruS[base+5];
        }
        float r = 1.f/(1.f + expf(-(ir + hr)));
        float z = 1.f/(1.f + expf(-(iz + hz)));
        float n = tanhf(inn + r*hn);
        float hp = init ? h0[b*HH + kk] : hprevT[(kk>>2)*128 + b*4 + (kk&3)];
        stf(&hTout[(kk>>2)*128 + b*4 + (kk&3)], (1.f - z)*n + z*hp);
    }
}

__global__ __launch_bounds__(NT3)
void fused6(const float* __restrict__ emb,
            const float* __restrict__ Wih, const float* __restrict__ bih,
            const float* __restrict__ Whh, const float* __restrict__ bhh,
            const float* __restrict__ Wout, const float* __restrict__ bout,
            const float* __restrict__ h0,
            float* __restrict__ out, float* __restrict__ ws)
{
    const int blk = blockIdx.x, tid = threadIdx.x;

    float* Hb = ws + H_OFF;
    float* Pb = ws + P_OFF;
    float* Fb = ws + F_OFF;
    int*  pflag = (int*)(ws + FLAG_OFF) + PF_OFF;
    int*  fflag = (int*)(ws + FLAG_OFF) + FF_OFF;
    int*  hflag = (int*)(ws + FLAG_OFF) + HF_OFF;

    float* w_pro  = out;
    float* w_o    = out + OUT_WO;
    float* emb_sq = out + OUT_EMB;
    float* len_o  = out + OUT_LEN;

    __shared__ SmemT sm;
    float* gruS = (float*)sm.redSm;          // alias (phases don't overlap)

    const bool is_red = (blk < BB);
    const bool is_gru = (blk >= 64 && blk < 192);
    int flag_reg = 0;
    int len_b = 0;

    // ---- h(0) = GRU(emb[GO], h0) -> H[0]
    if (is_gru) {
        gru_phase(blk-64, tid, true, sm.toksS, emb, Wih, bih, Whh, bhh, h0, nullptr,
                  Hb + 0*H_STEP, gruS);
        __syncthreads();                      // drains the atomic h stores (vmcnt)
        if (tid == 0) sti(&hflag[0*128 + (blk-64)], 1);
    }

    const int bgrp  = tid & 15;        // 16 batch-pairs
    const int rslot = tid >> 4;        // 0..31 row groups (4 rows each)
    const int b0    = bgrp*2;
    const int v0    = blk*RPB;
    const float4* W4 = (const float4*)Wout;

    for (int t = 0; t < TT; ++t) {
        const float* hT  = Hb + (unsigned)t*H_STEP;
        const float4* hT4 = (const float4*)hT;

        // ---- pre-stage W chunk 0 (h-independent) while h(t) may still be in flight
        {
#pragma unroll
            for (int i = 0; i < 2; ++i) {
                int off = i*512 + tid;            // 0..1023
                int r = off >> 3, k4 = off & 7;
                sm.wbuf[0][r*WROW + k4] = W4[(size_t)(v0 + r)*128 + k4];
            }
        }
        // ---- wait for h(t): parallel per-producer flag poll (relaxed, no inv storm)
        if (tid < 128) {
            while (ldi(&hflag[t*128 + tid]) == 0) __builtin_amdgcn_s_sleep(2);
        }
        // one targeted acquire per step: invalidate stale L1/L2 before reading h payload
        __builtin_amdgcn_fence(__ATOMIC_ACQUIRE, "agent");
        __syncthreads();

        // ================= Phase L: logits (128 rows x 32 batch) into registers =================
        float acc0[4] = {0.f,0.f,0.f,0.f};
        float acc1[4] = {0.f,0.f,0.f,0.f};

        for (int c = 0; c < NCH; ++c) {
            float4 st[2];
            if (c < NCH-1) {
#pragma unroll
                for (int i = 0; i < 2; ++i) {
                    int off = i*512 + tid;
                    int r = off >> 3, k4 = off & 7;
                    st[i] = W4[(size_t)(v0 + r)*128 + (c+1)*8 + k4];
                }
            }
            const float4* wb = sm.wbuf[c & 1];
#pragma unroll
            for (int c4 = 0; c4 < 8; ++c4) {
                const int c4g = c*8 + c4;
                float4 h0v = hT4[c4g*32 + b0];
                float4 h1v = hT4[c4g*32 + b0 + 1];
#pragma unroll
                for (int i = 0; i < 4; ++i) {
                    float4 w = wb[(rslot*4 + i)*WROW + c4];
                    acc0[i] += w.x*h0v.x + w.y*h0v.y + w.z*h0v.z + w.w*h0v.w;
                    acc1[i] += w.x*h1v.x + w.y*h1v.y + w.z*h1v.z + w.w*h1v.w;
                }
            }
            if (c < NCH-1) {
#pragma unroll
                for (int i = 0; i < 2; ++i) {
                    int off = i*512 + tid;
                    int r = off >> 3, k4 = off & 7;
                    sm.wbuf[(c+1) & 1][r*WROW + k4] = st[i];
                }
            }
            __syncthreads();
        }

        // epilogue: bias, per-thread softmax/argmax partials (logits stay in regs)
        {
            const int vb = v0 + rslot*4;
#pragma unroll
            for (int i = 0; i < 4; ++i) {
                float bb_ = bout[vb + i];
                acc0[i] += bb_; acc1[i] += bb_;
            }
            float m0 = NEG_SENT, s0 = 0.f, av0 = NEG_SENT; int ai0 = 0x7fffffff;
            float m1 = NEG_SENT, s1 = 0.f, av1 = NEG_SENT; int ai1 = 0x7fffffff;
#pragma unroll
            for (int i = 0; i < 4; ++i) {
                int v = vb + i;
                float val = acc0[i];
                if (val > m0) { s0 = s0*expf(m0 - val) + 1.f; m0 = val; }
                else          { s0 += expf(val - m0); }
                if (v >= 2 && val > av0) { av0 = val; ai0 = v; }
                float vl1 = acc1[i];
                if (vl1 > m1) { s1 = s1*expf(m1 - vl1) + 1.f; m1 = vl1; }
                else          { s1 += expf(vl1 - m1); }
                if (v >= 2 && vl1 > av1) { av1 = vl1; ai1 = v; }
            }
            sm.redSm[b0*32 + rslot]     = make_float4(m0, s0, av0, __int_as_float(ai0));
            sm.redSm[(b0+1)*32 + rslot] = make_float4(m1, s1, av1, __int_as_float(ai1));
        }
        __syncthreads();
        if (tid < 32) {   // merge 32 rslots for batch tid; publish via relaxed atomics
            float4 p0 = sm.redSm[tid*32];
            float m = p0.x, s = p0.y, av = p0.z; int ai = __float_as_int(p0.w);
            for (int j = 1; j < 32; ++j) {
                float4 p = sm.redSm[tid*32 + j];
                merge_sm(m, s, av, ai, p.x, p.y, p.z, __float_as_int(p.w));
            }
            float* dst = Pb + (size_t)t*P_STEP + blk*128 + tid*4;
            stf(dst+0, m); stf(dst+1, s); stf(dst+2, av); stf(dst+3, __int_as_float(ai));
        }
        __syncthreads();                      // drain partial stores (vmcnt)
        if (tid == 0) sti(&pflag[t*250 + blk], 1);

        // ================= reducers: blocks 0..31 finalize their own batch =================
        if (is_red) {
            if (tid < NB3) {
                while (ldi(&pflag[t*250 + tid]) == 0) __builtin_amdgcn_s_sleep(2);
            }
            __syncthreads();
            // empty lanes use finite sentinel: -INF pairs produce exp(NaN) in the butterfly
            float m = NEG_SENT, s = 0.f, av = NEG_SENT; int ai = 0x7fffffff;
            if (tid < NB3) {
                const float* p = Pb + (size_t)t*P_STEP + tid*128 + blk*4;
                m  = ldf(p+0); s = ldf(p+1); av = ldf(p+2); ai = __float_as_int(ldf(p+3));
            }
#pragma unroll
            for (int d = 1; d < 64; d <<= 1) {
                float m2  = __shfl_xor(m, d);
                float s2  = __shfl_xor(s, d);
                float av2 = __shfl_xor(av, d);
                int   ai2 = __shfl_xor(ai, d);
                merge_sm(m, s, av, ai, m2, s2, av2, ai2);
            }
            const int wid = tid >> 6, lane = tid & 63;
            if (lane == 0) sm.redSm[512 + wid] = make_float4(m, s, av, __int_as_float(ai));
            __syncthreads();
            if (tid == 0) {
                float4 p0 = sm.redSm[512];
                float M = p0.x, S = p0.y, AV = p0.z; int AI = __float_as_int(p0.w);
                for (int w2 = 1; w2 < 8; ++w2) {
                    float4 p = sm.redSm[512 + w2];
                    merge_sm(M, S, AV, AI, p.x, p.y, p.z, __float_as_int(p.w));
                }
                float* fd = Fb + (size_t)t*F_STEP + blk*4;
                stf(fd+0, M); stf(fd+1, 1.f/S); stf(fd+2, 0.f); stf(fd+3, __int_as_float(AI));
                asm volatile("s_waitcnt vmcnt(0)" ::: "memory");
                sti(&fflag[t*32 + blk], 1);
            }
        }

        // ================= everyone: wait finals, load m/s/tok =================
        if (tid < 32) {
            while (ldi(&fflag[t*32 + tid]) == 0) __builtin_amdgcn_s_sleep(2);
        }
        __syncthreads();
        if (tid < 32) {
            const float* f = Fb + (size_t)t*F_STEP + tid*4;
            sm.mprev[tid] = ldf(f+0); sm.sprev[tid] = ldf(f+1);
            sm.toksS[tid] = __float_as_int(ldf(f+3));
        }
        __syncthreads();

        // ---- GRU first (h(t+1) on the critical path ASAP)
        if (is_gru && t < TT-1) {
            gru_phase(blk-64, tid, false, sm.toksS, emb, Wih, bih, Whh, bhh, h0,
                      hT, Hb + (unsigned)(t+1)*H_STEP, gruS);
            __syncthreads();                  // drain atomic h stores
            if (tid == 0) sti(&hflag[(t+1)*128 + (blk-64)], 1);
        }

        // ---- outputs (blocks 0..31 own batch == blk)
        if (is_red) {
            const int tok   = sm.toksS[blk];
            const int alive = flag_reg ? 0 : 1;
            if (tid == 0) w_o[(size_t)t*BB + blk] = alive ? (float)tok : 0.f;
            len_b += alive;
            if (tid < EE) {
                float e = alive ? emb[(size_t)tok*EE + tid] : 0.f;
                emb_sq[(size_t)t*8192 + blk*EE + tid] = e;
            }
            flag_reg |= (tok == EOS_ID) ? 1 : 0;
            if (t == TT-1 && tid == 32) len_o[blk] = (float)len_b;
        }

        // ---- normalized w_pro write straight from registers
        {
            const int vb = v0 + rslot*4;
            float* wpt = w_pro + (size_t)t*1024000;
            float m0 = sm.mprev[b0],   si0 = sm.sprev[b0];
            float m1 = sm.mprev[b0+1], si1 = sm.sprev[b0+1];
            float4 o0 = make_float4(expf(acc0[0]-m0)*si0, expf(acc0[1]-m0)*si0,
                                    expf(acc0[2]-m0)*si0, expf(acc0[3]-m0)*si0);
            float4 o1 = make_float4(expf(acc1[0]-m1)*si1, expf(acc1[1]-m1)*si1,
                                    expf(acc1[2]-m1)*si1, expf(acc1[3]-m1)*si1);
            *(float4*)(wpt + (size_t)b0*VV + vb)     = o0;
            *(float4*)(wpt + (size_t)(b0+1)*VV + vb) = o1;
        }
        __syncthreads();   // sm reuse safety before next iteration
    }
}

// ======================= fallback multi-launch path (round-2, proven) =======================
#define NBL 500
#define NT  256
#define WS_HT0   0
#define WS_HT1   16384
#define WS_X     32768
#define WS_PART  40960
#define WS_M     104960
#define WS_SINV  104992
#define WS_INT   105024

__global__ __launch_bounds__(NT)
void k_init(const float* __restrict__ emb, float* __restrict__ ws)
{
    float* xbuf = ws + WS_X;
    int* toki  = (int*)(ws + WS_INT);
    int* flags = toki;
    int* lenac = toki + 32;
    xbuf[blockIdx.x*EE + threadIdx.x] = emb[GO_ID*EE + threadIdx.x];
    if (blockIdx.x == 0 && threadIdx.x < BB) { flags[threadIdx.x] = 0; lenac[threadIdx.x] = 0; }
}

__global__ __launch_bounds__(NT)
void k_gru(const float* __restrict__ Wih, const float* __restrict__ bih,
           const float* __restrict__ Whh, const float* __restrict__ bhh,
           const float* __restrict__ h0, float* __restrict__ ws, int t)
{
    const int blk = blockIdx.x, tid = threadIdx.x;
    float* hTprev = ws + (((t & 1) == 0) ? WS_HT1 : WS_HT0);
    float* hTcur  = ws + (((t & 1) == 0) ? WS_HT0 : WS_HT1);
    const float* xbuf = ws + WS_X;

    __shared__ float smem[1536];

    const int b    = tid & 31;
    const int q    = tid >> 5;
    const int k    = blk*4 + (q & 3);
    const int half = q >> 2;

    float s_ir = 0.f, s_iz = 0.f, s_in = 0.f;
    {
        const float4* x4 = (const float4*)xbuf + b*64;
        const float4* wr = (const float4*)Wih + (size_t)k*64;
        const float4* wz = (const float4*)Wih + (size_t)(HH + k)*64;
        const float4* wn = (const float4*)Wih + (size_t)(2*HH + k)*64;
        const int c0 = half*32, c1 = c0 + 32;
        for (int c4 = c0; c4 < c1; ++c4) {
            float4 xv = x4[c4];
            float4 a  = wr[c4]; s_ir += a.x*xv.x + a.y*xv.y + a.z*xv.z + a.w*xv.w;
            float4 bz = wz[c4]; s_iz += bz.x*xv.x + bz.y*xv.y + bz.z*xv.z + bz.w*xv.w;
            float4 cn = wn[c4]; s_in += cn.x*xv.x + cn.y*xv.y + cn.z*xv.z + cn.w*xv.w;
        }
    }
    float s_hr = 0.f, s_hz = 0.f, s_hn = 0.f;
    {
        const float4* wr = (const float4*)Whh + (size_t)k*128;
        const float4* wz = (const float4*)Whh + (size_t)(HH + k)*128;
        const float4* wn = (const float4*)Whh + (size_t)(2*HH + k)*128;
        const int c0 = half*64, c1 = c0 + 64;
        if (t == 0) {
            const float4* h4 = (const float4*)h0 + b*128;
            for (int c4 = c0; c4 < c1; ++c4) {
                float4 hv = h4[c4];
                float4 a  = wr[c4]; s_hr += a.x*hv.x + a.y*hv.y + a.z*hv.z + a.w*hv.w;
                float4 bz = wz[c4]; s_hz += bz.x*hv.x + bz.y*hv.y + bz.z*hv.z + bz.w*hv.w;
                float4 cn = wn[c4]; s_hn += cn.x*hv.x + cn.y*hv.y + cn.z*hv.z + cn.w*hv.w;
            }
        } else {
            const float4* h4 = (const float4*)hTprev;
            for (int c4 = c0; c4 < c1; ++c4) {
                float4 hv = h4[c4*32 + b];
                float4 a  = wr[c4]; s_hr += a.x*hv.x + a.y*hv.y + a.z*hv.z + a.w*hv.w;
                float4 bz = wz[c4]; s_hz += bz.x*hv.x + bz.y*hv.y + bz.z*hv.z + bz.w*hv.w;
                float4 cn = wn[c4]; s_hn += cn.x*hv.x + cn.y*hv.y + cn.z*hv.z + cn.w*hv.w;
            }
        }
    }
    const int si = (q*32 + b)*6;
    smem[si+0] = s_ir; smem[si+1] = s_iz; smem[si+2] = s_in;
    smem[si+3] = s_hr; smem[si+4] = s_hz; smem[si+5] = s_hn;
    __syncthreads();
    if (q < 4) {
        const int i0 = (q*32 + b)*6, i1 = ((q+4)*32 + b)*6;
        float ir  = smem[i0+0] + smem[i1+0] + bih[k];
        float iz  = smem[i0+1] + smem[i1+1] + bih[HH + k];
        float inn = smem[i0+2] + smem[i1+2] + bih[2*HH + k];
        float hr  = smem[i0+3] + smem[i1+3] + bhh[k];
        float hz  = smem[i0+4] + smem[i1+4] + bhh[HH + k];
        float hn  = smem[i0+5] + smem[i1+5] + bhh[2*HH + k];
        float r = 1.f/(1.f + expf(-(ir + hr)));
        float z = 1.f/(1.f + expf(-(iz + hz)));
        float n = tanhf(inn + r*hn);
        float hp = (t == 0) ? h0[b*HH + k] : hTprev[(k>>2)*128 + b*4 + (k&3)];
        float hv = (1.f - z)*n + z*hp;
        hTcur[(k>>2)*128 + b*4 + (k&3)] = hv;
    }
}

__global__ __launch_bounds__(NT)
void k_logits(const float* __restrict__ Wout, const float* __restrict__ bout,
              float* __restrict__ out, float* __restrict__ ws, int t)
{
    const int blk = blockIdx.x, tid = threadIdx.x;
    const float* hTcur = ws + (((t & 1) == 0) ? WS_HT0 : WS_HT1);
    float* part  = ws + WS_PART;
    const float* Mrow  = ws + WS_M;
    const float* SinvA = ws + WS_SINV;
    float* w_pro = out;

    __shared__ float smem[2080];

    if (t > 0) {
        float* wp = w_pro + (size_t)(t-1)*1024000 + blk*64;
        const int vl = tid & 63, bq = tid >> 6;
#pragma unroll
        for (int r = 0; r < 8; ++r) {
            int b = r*4 + bq;
            size_t idx = (size_t)b*VV + vl;
            wp[idx] = expf(wp[idx] - Mrow[b]) * SinvA[b];
        }
    }

    const int b  = tid & 31;
    const int vg = tid >> 5;
    const int v0 = blk*64 + vg*8;
    float acc[8] = {0.f,0.f,0.f,0.f,0.f,0.f,0.f,0.f};
    const float4* hT4  = (const float4*)hTcur;
    const float4* wrow = (const float4*)Wout + (size_t)v0*128;
    for (int c4 = 0; c4 < 128; ++c4) {
        float4 hv = hT4[c4*32 + b];
#pragma unroll
        for (int i = 0; i < 8; ++i) {
            float4 wv = wrow[(size_t)i*128 + c4];
            acc[i] += wv.x*hv.x + wv.y*hv.y + wv.z*hv.z + wv.w*hv.w;
        }
    }
    __syncthreads();
#pragma unroll
    for (int i = 0; i < 8; ++i)
        smem[b*65 + vg*8 + i] = acc[i] + bout[v0 + i];
    __syncthreads();
    {
        float* wp = w_pro + (size_t)t*1024000 + blk*64;
        const int vl = tid & 63, bq = tid >> 6;
#pragma unroll
        for (int r = 0; r < 8; ++r) {
            int b2 = r*4 + bq;
            wp[(size_t)b2*VV + vl] = smem[b2*65 + vl];
        }
    }
    {
        const int rb = tid >> 3, l = tid & 7;
        float m = -INFINITY, s = 0.f, av = -INFINITY; int ai = 0;
        for (int j = l; j < 64; j += 8) {
            float val = smem[rb*65 + j];
            if (val > m) { s = s*expf(m - val) + 1.f; m = val; }
            else         { s += expf(val - m); }
            int vglob = blk*64 + j;
            if (vglob >= 2 && val > av) { av = val; ai = vglob; }
        }
        for (int d = 1; d < 8; d <<= 1) {
            float m2  = __shfl_xor(m, d);
            float s2  = __shfl_xor(s, d);
            float av2 = __shfl_xor(av, d);
            int   ai2 = __shfl_xor(ai, d);
            float mn = fmaxf(m, m2);
            s = s*expf(m - mn) + s2*expf(m2 - mn); m = mn;
            if (av2 > av || (av2 == av && ai2 < ai)) { av = av2; ai = ai2; }
        }
        if (l == 0)
            ((float4*)part)[blk*32 + rb] = make_float4(m, s, av, __int_as_float(ai));
    }
}

__global__ __launch_bounds__(NT)
void k_reduce(const float* __restrict__ emb, float* __restrict__ out,
              float* __restrict__ ws, int t)
{
    const int b = blockIdx.x, tid = threadIdx.x;
    const float* part = ws + WS_PART;
    float* Mrow  = ws + WS_M;
    float* SinvA = ws + WS_SINV;
    int*   flags = (int*)(ws + WS_INT);
    int*   lenac = flags + 32;
    float* xbuf  = ws + WS_X;

    float* w_o    = out + OUT_WO;
    float* emb_sq = out + OUT_EMB;
    float* len_o  = out + OUT_LEN;

    __shared__ float smem[32];

    float m = -INFINITY, s = 0.f, av = -INFINITY; int ai = 0;
    for (int j = tid; j < NBL; j += NT) {
        float4 p = ((const float4*)part)[j*32 + b];
        float mn = fmaxf(m, p.x);
        s = s*expf(m - mn) + p.y*expf(p.x - mn); m = mn;
        int aij = __float_as_int(p.w);
        if (p.z > av || (p.z == av && aij < ai)) { av = p.z; ai = aij; }
    }
    for (int d = 1; d < 64; d <<= 1) {
        float m2  = __shfl_xor(m, d);
        float s2  = __shfl_xor(s, d);
        float av2 = __shfl_xor(av, d);
        int   ai2 = __shfl_xor(ai, d);
        float mn = fmaxf(m, m2);
        s = s*expf(m - mn) + s2*expf(m2 - mn); m = mn;
        if (av2 > av || (av2 == av && ai2 < ai)) { av = av2; ai = ai2; }
    }
    const int wid = tid >> 6, lane = tid & 63;
    if (lane == 0) {
        smem[wid*4+0] = m; smem[wid*4+1] = s;
        smem[wid*4+2] = av; smem[wid*4+3] = __int_as_float(ai);
    }
    __syncthreads();
    if (tid == 0) {
        float M = smem[0], S = smem[1], AV = smem[2];
        int AI = __float_as_int(smem[3]);
        for (int w2 = 1; w2 < 4; ++w2) {
            float m2 = smem[w2*4], s2 = smem[w2*4+1], av2 = smem[w2*4+2];
            int ai2 = __float_as_int(smem[w2*4+3]);
            float mn = fmaxf(M, m2);
            S = S*expf(M - mn) + s2*expf(m2 - mn); M = mn;
            if (av2 > AV || (av2 == AV && ai2 < AI)) { AV = av2; AI = ai2; }
        }
        Mrow[b] = M; SinvA[b] = 1.f/S;
        int fl = flags[b];
        int alive = fl ? 0 : 1;
        w_o[t*BB + b] = alive ? (float)AI : 0.f;
        flags[b] = fl | (AI == EOS_ID ? 1 : 0);
        lenac[b] += alive;
        if (t == TT-1) len_o[b] = (float)lenac[b];
        smem[16] = __int_as_float(AI);
        smem[17] = (float)alive;
    }
    __syncthreads();
    const int tok = __float_as_int(smem[16]);
    const float alive = smem[17];
    float e = emb[(size_t)tok*EE + tid];
    xbuf[b*EE + tid] = e;
    emb_sq[(size_t)t*8192 + b*EE + tid] = alive * e;
}

__global__ __launch_bounds__(NT)
void k_norm_last(float* __restrict__ out, float* __restrict__ ws)
{
    const int blk = blockIdx.x, tid = threadIdx.x;
    const float* Mrow  = ws + WS_M;
    const float* SinvA = ws + WS_SINV;
    float* wp = out + (size_t)(TT-1)*1024000 + blk*64;
    const int vl = tid & 63, bq = tid >> 6;
#pragma unroll
    for (int r = 0; r < 8; ++r) {
        int b = r*4 + bq;
        size_t idx = (size_t)b*VV + vl;
        wp[idx] = expf(wp[idx] - Mrow[b]) * SinvA[b];
    }
}

extern "C" void kernel_launch(void* const* d_in, const int* in_sizes, int n_in,
                              void* d_out, int out_size, void* d_ws, size_t ws_size,
                              hipStream_t stream)
{
    const float* emb  = (const float*)d_in[0];
    const float* Wih  = (const float*)d_in[1];
    const float* bih  = (const float*)d_in[2];
    const float* Whh  = (const float*)d_in[3];
    const float* bhh  = (const float*)d_in[4];
    const float* Wout = (const float*)d_in[5];
    const float* bout = (const float*)d_in[6];
    const float* h0   = (const float*)d_in[7];
    float* out = (float*)d_out;
    float* ws  = (float*)d_ws;

    hipError_t err = hipErrorOutOfMemory;
    if (ws_size >= WS_NEEDED_BYTES) {
        // zero the flag arena (stream-ordered; part of the captured graph)
        err = hipMemsetAsync((char*)d_ws + (size_t)FLAG_OFF*4, 0, (size_t)FLAG_INTS*4, stream);
        if (err == hipSuccess) {
            void* args[] = { (void*)&emb, (void*)&Wih, (void*)&bih, (void*)&Whh, (void*)&bhh,
                             (void*)&Wout, (void*)&bout, (void*)&h0, (void*)&out, (void*)&ws };
            err = hipLaunchCooperativeKernel((const void*)fused6,
                                             dim3(NB3), dim3(NT3), args, 0, stream);
        }
    }
    if (err != hipSuccess) {
        (void)hipGetLastError();   // clear sticky error; use proven multi-launch path
        hipLaunchKernelGGL(k_init, dim3(BB), dim3(NT), 0, stream, emb, ws);
        for (int t = 0; t < TT; ++t) {
            hipLaunchKernelGGL(k_gru,    dim3(128), dim3(NT), 0, stream, Wih, bih, Whh, bhh, h0, ws, t);
            hipLaunchKernelGGL(k_logits, dim3(NBL), dim3(NT), 0, stream, Wout, bout, out, ws, t);
            hipLaunchKernelGGL(k_reduce, dim3(BB),  dim3(NT), 0, stream, emb, out, ws, t);
        }
        hipLaunchKernelGGL(k_norm_last, dim3(NBL), dim3(NT), 0, stream, out, ws);
    }
}